// Round 10
// baseline (266.456 us; speedup 1.0000x reference)
//
#include <hip/hip_runtime.h>
#include <hip/hip_bf16.h>
#include <cstdint>

typedef __bf16 bf16;
typedef __bf16 bf16x8 __attribute__((ext_vector_type(8)));
typedef float  f32x4  __attribute__((ext_vector_type(4)));

// ---------- new-path workspace layout (needs >= 140113920 B) ----------
#define N_ENCB   0u            // 64M bf16 = 128 MB
#define N_W1BT   134217728u    // 2 MB
#define N_C      136314880u    // 128 KB
#define N_E      136445952u    // 256 KB
#define N_ALPHA  136707072u    // 256 KB
#define N_HIDP   136968192u    // 1 MB (unused in new path)
#define N_CTXP   138016768u    // 2 MB (unused in new path)
#define N_TOTAL  140113920ull

// ---------- old-path (fallback) layout ----------
#define O_W1BT   0u
#define O_C      2097152u
#define O_E      2228224u
#define O_ALPHA  2490368u
#define O_HIDP   2752512u
#define O_CTXP   3801088u

// ---------------- enc f32 -> bf16 ----------------
__global__ void k_convert(const float* __restrict__ in, bf16* __restrict__ out) {
    size_t i = ((size_t)blockIdx.x * 256 + threadIdx.x) * 8;
    const size_t stride = (size_t)2048 * 256 * 8;
    for (; i < 67108864ull; i += stride) {
        f32x4 a = *(const f32x4*)(in + i);
        f32x4 b = *(const f32x4*)(in + i + 4);
        bf16x8 o;
        o[0]=(bf16)a[0]; o[1]=(bf16)a[1]; o[2]=(bf16)a[2]; o[3]=(bf16)a[3];
        o[4]=(bf16)b[0]; o[5]=(bf16)b[1]; o[6]=(bf16)b[2]; o[7]=(bf16)b[3];
        *(bf16x8*)(out + i) = o;
    }
}

// ---------------- fused pre-pass: w1t | cvec=b1 + ebuf=0 | out=0 ----------------
__global__ __launch_bounds__(256) void k_pre(const float* __restrict__ W1,
                                             const float* __restrict__ b1,
                                             bf16* __restrict__ w1bt,
                                             float* __restrict__ cvec,
                                             float* __restrict__ ebuf,
                                             float* __restrict__ out) {
    int bid = blockIdx.x, t = threadIdx.x;
    if (bid < 1024) {
        // W1_enc (k x n) -> w1bt (n x k) bf16, 32x32 tile via LDS
        __shared__ float tile[32][33];
        int bx = bid & 31, by = bid >> 5;
        int tx = t & 31, ty = t >> 5;     // 32 x 8
#pragma unroll
        for (int i = 0; i < 4; ++i)
            tile[ty + i * 8][tx] = W1[(size_t)(by * 32 + ty + i * 8) * 1024 + bx * 32 + tx];
        __syncthreads();
#pragma unroll
        for (int i = 0; i < 4; ++i)
            w1bt[(size_t)(bx * 32 + ty + i * 8) * 1024 + by * 32 + tx] = (bf16)tile[tx][ty + i * 8];
    } else if (bid < 1408) {
        int idx = (bid - 1024) * 256 + t;         // 0 .. 98303
        if (idx < 32768) cvec[idx] = b1[idx & 1023];
        else             ebuf[idx - 32768] = 0.f;
    } else {
        out[(bid - 1408) * 256 + t] = 0.f;        // 32768 floats
    }
}

// ---------------- hid_proj: atomic accumulate into cvec ----------------
__global__ void k_hid_atomic(const float* __restrict__ hid, const float* __restrict__ W1,
                             float* __restrict__ cvec) {
    int e = blockIdx.x * 256 + threadIdx.x;   // grid (4, 32)
    int dch = blockIdx.y;
    float acc[32];
#pragma unroll
    for (int b = 0; b < 32; ++b) acc[b] = 0.f;
    int d0 = dch * 32;
#pragma unroll 4
    for (int dd = 0; dd < 32; ++dd) {
        int d = d0 + dd;
        float w = W1[(size_t)(1024 + d) * 1024 + e];
#pragma unroll
        for (int b = 0; b < 32; ++b) acc[b] += hid[b * 1024 + d] * w;
    }
#pragma unroll
    for (int b = 0; b < 32; ++b) atomicAdd(&cvec[b * 1024 + e], acc[b]);
}

// ---------------- fallback hid_proj ----------------
__global__ void k_hid_partial(const float* __restrict__ hid, const float* __restrict__ W1,
                              float* __restrict__ hidp) {
    int e = blockIdx.x * 256 + threadIdx.x;
    int dch = blockIdx.y;
    float acc[32];
#pragma unroll
    for (int b = 0; b < 32; ++b) acc[b] = 0.f;
    int d0 = dch * 128;
    for (int dd = 0; dd < 128; ++dd) {
        int d = d0 + dd;
        float w = W1[(size_t)(1024 + d) * 1024 + e];
#pragma unroll
        for (int b = 0; b < 32; ++b) acc[b] += hid[b * 1024 + d] * w;
    }
#pragma unroll
    for (int b = 0; b < 32; ++b) hidp[((size_t)dch * 32 + b) * 1024 + e] = acc[b];
}

__global__ void k_hid_reduce(const float* __restrict__ hidp, const float* __restrict__ b1,
                             float* __restrict__ cvec) {
    int i = blockIdx.x * 256 + threadIdx.x;
    int e = i & 1023;
    float s = b1[e];
#pragma unroll
    for (int dch = 0; dch < 8; ++dch) s += hidp[(size_t)dch * 32768 + i];
    cvec[i] = s;
}

// ---------------- fallback W1 transpose ----------------
__global__ void k_w1t(const float* __restrict__ W1, bf16* __restrict__ w1bt) {
    __shared__ float tile[32][33];
    int tx = threadIdx.x, ty = threadIdx.y;
    int bx = blockIdx.x, by = blockIdx.y;
#pragma unroll
    for (int i = 0; i < 4; ++i)
        tile[ty + i * 8][tx] = W1[(size_t)(by * 32 + ty + i * 8) * 1024 + bx * 32 + tx];
    __syncthreads();
#pragma unroll
    for (int i = 0; i < 4; ++i)
        w1bt[(size_t)(bx * 32 + ty + i * 8) * 1024 + by * 32 + tx] = (bf16)tile[tx][ty + i * 8];
}

__device__ inline float fast_tanh(float x) {
    float e2 = __expf(2.f * x);
    return 1.f - 2.f / (e2 + 1.f);
}

// ================= persistent 256x256 bf16 GEMM, 4-region schedule (R4-best, FROZEN) =====
#define SBAR  __builtin_amdgcn_s_barrier()
#define VMC4  asm volatile("s_waitcnt vmcnt(4)" ::: "memory")
#define PRIO1 __builtin_amdgcn_s_setprio(1)
#define PRIO0 __builtin_amdgcn_s_setprio(0)

template<int D, int MH>
__device__ __forceinline__ void rdA(const char* pA0, const char* pA1, bf16x8 (&bA)[4][2]) {
#pragma unroll
    for (int m = 0; m < 4; ++m) {
        bA[m][0] = *(const bf16x8*)(pA0 + D * 32768 + MH * 8192 + m * 2048);
        bA[m][1] = *(const bf16x8*)(pA1 + D * 32768 + MH * 8192 + m * 2048);
    }
}
template<int D, int N0>
__device__ __forceinline__ void rdB(const char* pB0, const char* pB1, bf16x8 (&bB)[4][2]) {
#pragma unroll
    for (int n = 0; n < 2; ++n) {
        bB[N0 + n][0] = *(const bf16x8*)(pB0 + D * 32768 + (N0 + n) * 2048);
        bB[N0 + n][1] = *(const bf16x8*)(pB1 + D * 32768 + (N0 + n) * 2048);
    }
}
// kk-outer: dependent MFMA pairs spaced by 8 independent instructions
template<int MH, int NH>
__device__ __forceinline__ void mfmaQ(bf16x8 (&bA)[4][2], bf16x8 (&bB)[4][2], f32x4 (&acc)[8][4]) {
#pragma unroll
    for (int kk = 0; kk < 2; ++kk)
#pragma unroll
        for (int m = 0; m < 4; ++m)
#pragma unroll
            for (int n = 0; n < 2; ++n)
                acc[MH * 4 + m][NH * 2 + n] = __builtin_amdgcn_mfma_f32_16x16x32_bf16(
                    bA[m][kk], bB[NH * 2 + n][kk], acc[MH * 4 + m][NH * 2 + n], 0, 0, 0);
}

__global__ __launch_bounds__(512, 1) void k_gemm8(
    const bf16* __restrict__ encb, const bf16* __restrict__ w1bt,
    const float* __restrict__ cvec, const float* __restrict__ w2,
    float* __restrict__ ebuf)
{
    __shared__ __align__(16) char smem[131072];
    const int t = threadIdx.x;
    const int lane = t & 63;
    const int w  = t >> 6;
    const int wr = w >> 2;
    const int wc = w & 3;
    const int l15 = lane & 15, g = (lane >> 4) & 3;

    // persistent: nt constant per block (B panel fixed), mt steps by 8 per assignment
    unsigned bidx = blockIdx.x;               // 256 blocks
    unsigned swz0 = (bidx & 7u) * 128u + (bidx >> 3);
    const int nt  = swz0 & 3;
    const int mt0 = swz0 >> 2;
    const int n0  = nt * 256;

    const int r6  = t >> 3;
    const int gsl = (t & 7) ^ (r6 & 7);
    const char* srcA    = (const char*)encb + (size_t)(mt0 * 256 + r6) * 2048 + gsl * 16;
    const char* srcA_nx = srcA + (size_t)2048 * 2048;
    const char* srcB    = (const char*)w1bt + (size_t)(n0 + r6) * 2048 + gsl * 16;

#define STAGE_A(SRC, D, H, KT) do { \
    const char* _s = (SRC) + (size_t)(H) * 262144 + (size_t)(KT) * 128; \
    __builtin_amdgcn_global_load_lds((const __attribute__((address_space(1))) unsigned int*)_s, \
        (__attribute__((address_space(3))) unsigned int*)(smem + (D) * 32768 + (H) * 16384 + w * 1024), 16, 0, 0); \
    __builtin_amdgcn_global_load_lds((const __attribute__((address_space(1))) unsigned int*)(_s + 131072), \
        (__attribute__((address_space(3))) unsigned int*)(smem + (D) * 32768 + (H) * 16384 + 8192 + w * 1024), 16, 0, 0); \
} while (0)
#define STAGE_B(D, H, KT) do { \
    const char* _s = srcB + (size_t)(H) * 262144 + (size_t)(KT) * 128; \
    __builtin_amdgcn_global_load_lds((const __attribute__((address_space(1))) unsigned int*)_s, \
        (__attribute__((address_space(3))) unsigned int*)(smem + 65536 + (D) * 32768 + (H) * 16384 + w * 1024), 16, 0, 0); \
    __builtin_amdgcn_global_load_lds((const __attribute__((address_space(1))) unsigned int*)(_s + 131072), \
        (__attribute__((address_space(3))) unsigned int*)(smem + 65536 + (D) * 32768 + (H) * 16384 + 8192 + w * 1024), 16, 0, 0); \
} while (0)

    const int rbA = wr * 128 + l15;
    const int rbB = wc * 64 + l15;
    const int sK0 = (g ^ (l15 & 7)) << 4;
    const int sK1 = sK0 ^ 64;
    const char* pA0 = smem + rbA * 128 + sK0;
    const char* pA1 = smem + rbA * 128 + sK1;
    const char* pB0 = smem + 65536 + rbB * 128 + sK0;
    const char* pB1 = smem + 65536 + rbB * 128 + sK1;

    f32x4 acc[8][4] = {};
    bf16x8 bA[4][2], bB[4][2];

    float wv[4];
    int gcol[4];
#pragma unroll
    for (int n = 0; n < 4; ++n) {
        gcol[n] = n0 + wc * 64 + n * 16 + l15;
        wv[n] = w2[gcol[n]];
    }

    // one-time prologue: tile0 A+B -> buf0, tile1 B -> buf1 (leaves 4 B-ops in flight)
    STAGE_A(srcA, 0, 0, 0); STAGE_A(srcA, 0, 1, 0);
    STAGE_B(0, 0, 0); STAGE_B(0, 1, 0);
    STAGE_B(1, 0, 1); STAGE_B(1, 1, 1);
    VMC4; SBAR;

#pragma unroll 1
    for (int j = 0; j < 4; ++j) {
#pragma unroll 1
        for (int i = 0; i < 8; ++i) {
            const int st1 = 2 * i + 1;
            const bool last = (i == 7);
            const int st2 = last ? 0 : 2 * i + 2;
            const int st3 = last ? 1 : 2 * i + 3;
            const char* sA2 = last ? ((j < 3) ? srcA_nx : srcA) : srcA;

            // R1: buf0 MH0, all NH. 16 ds_reads + stage A(t+1)->buf1 + 32 MFMA.
            rdA<0, 0>(pA0, pA1, bA);
            rdB<0, 0>(pB0, pB1, bB);
            rdB<0, 2>(pB0, pB1, bB);
            STAGE_A(srcA, 1, 0, st1);
            STAGE_A(srcA, 1, 1, st1);
            PRIO1; mfmaQ<0, 0>(bA, bB, acc); mfmaQ<0, 1>(bA, bB, acc); PRIO0;
            SBAR;   // all waves' buf0-B reads done before R2 restages buf0-B

            // R2: buf0 MH1 (B frags reused in regs). Stage B(t+2)->buf0. Drain D1.
            rdA<0, 1>(pA0, pA1, bA);
            STAGE_B(0, 0, st2);
            STAGE_B(0, 1, st2);
            PRIO1; mfmaQ<1, 0>(bA, bB, acc); mfmaQ<1, 1>(bA, bB, acc); PRIO0;
            VMC4;   // drains prev B-buf1 + this iter's A-buf1 (12 outstanding -> 4)
            SBAR;   // buf0-A reads done before R3 restages buf0-A; buf1 visible

            // R3: buf1 MH0. Stage A(t+2)->buf0.
            rdA<1, 0>(pA0, pA1, bA);
            rdB<1, 0>(pB0, pB1, bB);
            rdB<1, 2>(pB0, pB1, bB);
            STAGE_A(sA2, 0, 0, st2);
            STAGE_A(sA2, 0, 1, st2);
            PRIO1; mfmaQ<0, 0>(bA, bB, acc); mfmaQ<0, 1>(bA, bB, acc); PRIO0;
            SBAR;   // buf1-B reads done before R4 restages buf1-B

            // R4: buf1 MH1. Stage B(t+3)->buf1. Drain D2.
            rdA<1, 1>(pA0, pA1, bA);
            STAGE_B(1, 0, st3);
            STAGE_B(1, 1, st3);
            PRIO1; mfmaQ<1, 0>(bA, bB, acc); mfmaQ<1, 1>(bA, bB, acc); PRIO0;
            VMC4;   // drains B-buf0 + A-buf0 for next iter's R1/R2
            SBAR;
        }

        // epilogue for assignment j (4 B-ops for next tile remain in flight)
        const int m0j = (mt0 + 8 * j) * 256;
        const int bj  = m0j >> 11;
        float cv[4];
#pragma unroll
        for (int n = 0; n < 4; ++n) cv[n] = cvec[bj * 1024 + gcol[n]];
#pragma unroll
        for (int m = 0; m < 8; ++m) {
#pragma unroll
            for (int r = 0; r < 4; ++r) {
                float s = 0.f;
#pragma unroll
                for (int n = 0; n < 4; ++n)
                    s += fast_tanh(acc[m][n][r] + cv[n]) * wv[n];
                s += __shfl_xor(s, 1); s += __shfl_xor(s, 2);
                s += __shfl_xor(s, 4); s += __shfl_xor(s, 8);
                if (l15 == 0)
                    atomicAdd(&ebuf[m0j + wr * 128 + m * 16 + g * 4 + r], s);
            }
        }
#pragma unroll
        for (int m = 0; m < 8; ++m)
#pragma unroll
            for (int n = 0; n < 4; ++n)
                acc[m][n] = f32x4{0.f, 0.f, 0.f, 0.f};

        srcA = srcA_nx;
        srcA_nx += (size_t)2048 * 2048;
    }
#undef STAGE_A
#undef STAGE_B
}

// ================= old-path 128x128 f32-staging GEMM (fallback) =================
__global__ __launch_bounds__(256, 3) void k_gemm_e(
    const float* __restrict__ enc, const bf16* __restrict__ w1bt,
    const float* __restrict__ cvec, const float* __restrict__ w2,
    float* __restrict__ ebuf)
{
    __shared__ __align__(16) unsigned char smem[24 * 1024];
    const int t = threadIdx.x;
    const int lane = t & 63;
    const int w = t >> 6;
    const int wr = w >> 1, wc = w & 1;
    const int l15 = lane & 15, g = lane >> 4;

    unsigned raw = blockIdx.x;
    unsigned swz = (raw & 7u) * 512u + (raw >> 3);
    const int nt = swz & 7, mt = swz >> 3;
    const int m0 = mt * 128, n0 = nt * 128;
    const int b = m0 >> 11;

    int rowA = (t >> 3);
    int slotA = (t & 7) ^ (rowA & 7);
    const char* gA0 = (const char*)enc + (size_t)(m0 + rowA) * 4096 + slotA * 16;
    int rowB = (t >> 2);
    int slotB = (t & 3) ^ ((t >> 3) & 3);
    const char* gB0 = (const char*)w1bt + (size_t)(n0 + rowB) * 2048 + slotB * 16;

    int rowA0 = wr * 64 + l15;
    unsigned offA0 = (unsigned)rowA0 * 128 + ((((2 * g)) ^ (l15 & 7)) << 4);
    int rowB0 = wc * 64 + l15;
    unsigned offB0 = 16384u + (unsigned)rowB0 * 64 + (((g ^ ((l15 >> 1) & 3))) << 4);

    f32x4 acc[4][4] = {};

    for (int kt = 0; kt < 32; ++kt) {
        const char* pa = gA0 + kt * 128;
        const char* pb = gB0 + kt * 64;
#pragma unroll
        for (int c = 0; c < 4; ++c)
            __builtin_amdgcn_global_load_lds(
                (const __attribute__((address_space(1))) unsigned int*)(pa + (size_t)c * 131072),
                (__attribute__((address_space(3))) unsigned int*)(smem + c * 4096 + w * 1024), 16, 0, 0);
#pragma unroll
        for (int c = 0; c < 2; ++c)
            __builtin_amdgcn_global_load_lds(
                (const __attribute__((address_space(1))) unsigned int*)(pb + (size_t)c * 131072),
                (__attribute__((address_space(3))) unsigned int*)(smem + 16384 + c * 4096 + w * 1024), 16, 0, 0);
        __syncthreads();

        bf16x8 af[4], bfr[4];
#pragma unroll
        for (int m = 0; m < 4; ++m) {
            unsigned o0 = offA0 + m * 2048;
            f32x4 lo = *(const f32x4*)(smem + o0);
            f32x4 hi = *(const f32x4*)(smem + (o0 ^ 16u));
            bf16x8 a;
            a[0] = (bf16)lo[0]; a[1] = (bf16)lo[1]; a[2] = (bf16)lo[2]; a[3] = (bf16)lo[3];
            a[4] = (bf16)hi[0]; a[5] = (bf16)hi[1]; a[6] = (bf16)hi[2]; a[7] = (bf16)hi[3];
            af[m] = a;
        }
#pragma unroll
        for (int n = 0; n < 4; ++n)
            bfr[n] = *(const bf16x8*)(smem + (offB0 + n * 1024));
#pragma unroll
        for (int m = 0; m < 4; ++m)
#pragma unroll
            for (int n = 0; n < 4; ++n)
                acc[m][n] = __builtin_amdgcn_mfma_f32_16x16x32_bf16(af[m], bfr[n], acc[m][n], 0, 0, 0);
        __syncthreads();
    }

    float cv[4], wv[4];
#pragma unroll
    for (int n = 0; n < 4; ++n) {
        int gcol = n0 + wc * 64 + n * 16 + l15;
        cv[n] = cvec[b * 1024 + gcol];
        wv[n] = w2[gcol];
    }
#pragma unroll
    for (int m = 0; m < 4; ++m) {
#pragma unroll
        for (int r = 0; r < 4; ++r) {
            float s = 0.f;
#pragma unroll
            for (int n = 0; n < 4; ++n)
                s += fast_tanh(acc[m][n][r] + cv[n]) * wv[n];
            s += __shfl_xor(s, 1); s += __shfl_xor(s, 2);
            s += __shfl_xor(s, 4); s += __shfl_xor(s, 8);
            if (l15 == 0)
                atomicAdd(&ebuf[m0 + wr * 64 + m * 16 + g * 4 + r], s);
        }
    }
}

// ---------------- softmax ----------------
__global__ void k_softmax(const float* __restrict__ ebuf, float* __restrict__ alpha) {
    int bb = blockIdx.x, t = threadIdx.x;
    __shared__ float red[4], red2[4];
    float v[8];
    float mx = -1e30f;
#pragma unroll
    for (int i = 0; i < 8; ++i) { v[i] = ebuf[bb * 2048 + i * 256 + t]; mx = fmaxf(mx, v[i]); }
    for (int o = 32; o > 0; o >>= 1) mx = fmaxf(mx, __shfl_xor(mx, o));
    if ((t & 63) == 0) red[t >> 6] = mx;
    __syncthreads();
    mx = fmaxf(fmaxf(red[0], red[1]), fmaxf(red[2], red[3]));
    float sum = 0.f;
#pragma unroll
    for (int i = 0; i < 8; ++i) { v[i] = __expf(v[i] - mx); sum += v[i]; }
    for (int o = 32; o > 0; o >>= 1) sum += __shfl_xor(sum, o);
    if ((t & 63) == 0) red2[t >> 6] = sum;
    __syncthreads();
    sum = red2[0] + red2[1] + red2[2] + red2[3];
    float inv = 1.f / sum;
#pragma unroll
    for (int i = 0; i < 8; ++i) alpha[bb * 2048 + i * 256 + t] = v[i] * inv;
}

// ---------------- context from bf16 enc, atomic-direct to out ----------------
__global__ void k_ctx_atomic(const bf16* __restrict__ encb, const float* __restrict__ alpha,
                             float* __restrict__ out) {
    int bid = blockIdx.x;                     // 512 = 32 b x 16 sc
    int bb = bid >> 4, sc = bid & 15;
    int t = threadIdx.x;                      // 256
    __shared__ float al[128];
    __shared__ float red[128 * 8];
    if (t < 128) al[t] = alpha[bb * 2048 + sc * 128 + t];
    __syncthreads();
    int d0 = (t & 127) * 8;
    int sp = t >> 7;                          // 0/1 row parity
    float acc[8] = {};
    const bf16* base = encb + ((size_t)bb * 2048 + sc * 128 + sp) * 1024 + d0;
    for (int s = 0; s < 128; s += 2) {
        bf16x8 v = *(const bf16x8*)(base + (size_t)s * 1024);
        float a = al[s + sp];
#pragma unroll
        for (int k = 0; k < 8; ++k) acc[k] += a * (float)v[k];
    }
    if (sp == 1) {
#pragma unroll
        for (int k = 0; k < 8; ++k) red[(t & 127) * 8 + k] = acc[k];
    }
    __syncthreads();
    if (sp == 0) {
        float* o = out + (size_t)bb * 1024 + d0;
#pragma unroll
        for (int k = 0; k < 8; ++k) atomicAdd(&o[k], acc[k] + red[t * 8 + k]);
    }
}

// ---------------- fallback f32 context ----------------
__global__ void k_ctx_partial(const float* __restrict__ enc, const float* __restrict__ alpha,
                              float* __restrict__ ctxp) {
    int bid = blockIdx.x;
    int bb = bid >> 4, sc = bid & 15;
    int t = threadIdx.x;
    __shared__ float al[128];
    if (t < 128) al[t] = alpha[bb * 2048 + sc * 128 + t];
    __syncthreads();
    f32x4 acc = {0.f, 0.f, 0.f, 0.f};
    const f32x4* base = (const f32x4*)(enc + ((size_t)bb * 2048 + sc * 128) * 1024) + t;
    for (int s = 0; s < 128; ++s) {
        f32x4 vv = base[(size_t)s * 256];
        acc += vv * al[s];
    }
    *((f32x4*)(ctxp + (size_t)bid * 1024) + t) = acc;
}

__global__ void k_ctx_reduce(const float* __restrict__ ctxp, float* __restrict__ out) {
    int i = blockIdx.x * 256 + threadIdx.x;
    int bb = i >> 10, d = i & 1023;
    float s = 0.f;
#pragma unroll
    for (int sc = 0; sc < 16; ++sc) s += ctxp[((size_t)(bb * 16 + sc)) * 1024 + d];
    out[i] = s;
}

extern "C" void kernel_launch(void* const* d_in, const int* in_sizes, int n_in,
                              void* d_out, int out_size, void* d_ws, size_t ws_size,
                              hipStream_t stream) {
    const float* hid = (const float*)d_in[0];
    const float* enc = (const float*)d_in[1];
    const float* W1  = (const float*)d_in[2];
    const float* b1  = (const float*)d_in[3];
    const float* w2  = (const float*)d_in[4];
    float* out = (float*)d_out;
    char* ws = (char*)d_ws;

    if (ws_size >= N_TOTAL) {
        bf16*  encb  = (bf16*)(ws + N_ENCB);
        bf16*  w1bt  = (bf16*)(ws + N_W1BT);
        float* cvec  = (float*)(ws + N_C);
        float* ebuf  = (float*)(ws + N_E);
        float* alpha = (float*)(ws + N_ALPHA);

        k_pre<<<1536, 256, 0, stream>>>(W1, b1, w1bt, cvec, ebuf, out);
        k_convert<<<2048, 256, 0, stream>>>(enc, encb);
        k_hid_atomic<<<dim3(4, 32), 256, 0, stream>>>(hid, W1, cvec);
        k_gemm8<<<256, 512, 0, stream>>>(encb, w1bt, cvec, w2, ebuf);
        k_softmax<<<32, 256, 0, stream>>>(ebuf, alpha);
        k_ctx_atomic<<<512, 256, 0, stream>>>(encb, alpha, out);
    } else {
        bf16*  w1bt  = (bf16*)(ws + O_W1BT);
        float* cvec  = (float*)(ws + O_C);
        float* ebuf  = (float*)(ws + O_E);
        float* alpha = (float*)(ws + O_ALPHA);
        float* hidp  = (float*)(ws + O_HIDP);
        float* ctxp  = (float*)(ws + O_CTXP);

        hipMemsetAsync(ebuf, 0, 65536 * sizeof(float), stream);
        k_hid_partial<<<dim3(4, 8), 256, 0, stream>>>(hid, W1, hidp);
        k_w1t<<<dim3(32, 32), dim3(32, 8), 0, stream>>>(W1, w1bt);
        k_hid_reduce<<<128, 256, 0, stream>>>(hidp, b1, cvec);
        k_gemm_e<<<4096, 256, 0, stream>>>(enc, w1bt, cvec, w2, ebuf);
        k_softmax<<<32, 256, 0, stream>>>(ebuf, alpha);
        k_ctx_partial<<<512, 256, 0, stream>>>(enc, alpha, ctxp);
        k_ctx_reduce<<<128, 256, 0, stream>>>(ctxp, out);
    }
}

// Round 11
// 259.190 us; speedup vs baseline: 1.0280x; 1.0280x over previous
//
#include <hip/hip_runtime.h>
#include <hip/hip_bf16.h>
#include <cstdint>

typedef __bf16 bf16;
typedef __bf16 bf16x8 __attribute__((ext_vector_type(8)));
typedef float  f32x4  __attribute__((ext_vector_type(4)));

// ---------- new-path compact workspace ----------
#define P_W1BT   0u            // 1024*1024 bf16 = 2 MB
#define P_C      2097152u      // 32*1024 f32
#define P_E      2228224u      // 65536 f32
#define P_ALPHA  2490368u      // 65536 f32
#define P_TOTAL  2752512ull

// ---------- old-path (fallback) layout ----------
#define O_W1BT   0u
#define O_C      2097152u
#define O_E      2228224u
#define O_ALPHA  2490368u
#define O_HIDP   2752512u
#define O_CTXP   3801088u
#define O_TOTAL  5898240ull

// ---------------- fused pre-pass: w1t | cvec=b1 + ebuf=0 | out=0 ----------------
__global__ __launch_bounds__(256) void k_pre(const float* __restrict__ W1,
                                             const float* __restrict__ b1,
                                             bf16* __restrict__ w1bt,
                                             float* __restrict__ cvec,
                                             float* __restrict__ ebuf,
                                             float* __restrict__ out) {
    int bid = blockIdx.x, t = threadIdx.x;
    if (bid < 1024) {
        __shared__ float tile[32][33];
        int bx = bid & 31, by = bid >> 5;
        int tx = t & 31, ty = t >> 5;
#pragma unroll
        for (int i = 0; i < 4; ++i)
            tile[ty + i * 8][tx] = W1[(size_t)(by * 32 + ty + i * 8) * 1024 + bx * 32 + tx];
        __syncthreads();
#pragma unroll
        for (int i = 0; i < 4; ++i)
            w1bt[(size_t)(bx * 32 + ty + i * 8) * 1024 + by * 32 + tx] = (bf16)tile[tx][ty + i * 8];
    } else if (bid < 1408) {
        int idx = (bid - 1024) * 256 + t;
        if (idx < 32768) cvec[idx] = b1[idx & 1023];
        else             ebuf[idx - 32768] = 0.f;
    } else {
        out[(bid - 1408) * 256 + t] = 0.f;
    }
}

// ---------------- hid_proj: atomic accumulate into cvec ----------------
__global__ void k_hid_atomic(const float* __restrict__ hid, const float* __restrict__ W1,
                             float* __restrict__ cvec) {
    int e = blockIdx.x * 256 + threadIdx.x;
    int dch = blockIdx.y;
    float acc[32];
#pragma unroll
    for (int b = 0; b < 32; ++b) acc[b] = 0.f;
    int d0 = dch * 32;
#pragma unroll 4
    for (int dd = 0; dd < 32; ++dd) {
        int d = d0 + dd;
        float w = W1[(size_t)(1024 + d) * 1024 + e];
#pragma unroll
        for (int b = 0; b < 32; ++b) acc[b] += hid[b * 1024 + d] * w;
    }
#pragma unroll
    for (int b = 0; b < 32; ++b) atomicAdd(&cvec[b * 1024 + e], acc[b]);
}

__device__ inline float fast_tanh(float x) {
    float e2 = __expf(2.f * x);
    return 1.f - 2.f / (e2 + 1.f);
}

// ====== 256x256 bf16-MFMA GEMM with FUSED f32->bf16 A-convert ======
// BK=32; A staged as f32 (32 KB/tile), B bf16 (16 KB/tile); 3-buffer ring (144 KB);
// stage-ahead 2, one barrier/iter, counted vmcnt(6).
#define SBAR  __builtin_amdgcn_s_barrier()
#define VMC6  asm volatile("s_waitcnt vmcnt(6)" ::: "memory")
#define VMC0  asm volatile("s_waitcnt vmcnt(0)" ::: "memory")
#define PRIO1 __builtin_amdgcn_s_setprio(1)
#define PRIO0 __builtin_amdgcn_s_setprio(0)

__global__ __launch_bounds__(512, 1) void k_gemm9(
    const float* __restrict__ encf, const bf16* __restrict__ w1bt,
    const float* __restrict__ cvec, const float* __restrict__ w2,
    float* __restrict__ ebuf)
{
    __shared__ __align__(16) char smem[147456];   // 3 x (A 32KB | B 16KB)
    const int t = threadIdx.x;
    const int lane = t & 63;
    const int w  = t >> 6;
    const int wr = w >> 2;          // 0..1 (M half)
    const int wc = w & 3;           // 0..3 (N quarter)
    const int l15 = lane & 15, g = (lane >> 4) & 3;

    unsigned raw = blockIdx.x;                     // 1024 blocks
    unsigned swz = (raw & 7u) * 128u + (raw >> 3); // XCD-contiguous
    const int nt = swz & 3, mt = swz >> 2;
    const int m0 = mt * 256, n0 = nt * 256;
    const int b  = m0 >> 11;

    // staging source pointers (pre-swizzled: phys slot p holds logical p^(row&key))
    const int r6  = t >> 3;                        // A: 0..63, key row&7 (8 slots/128B row)
    const int gsA = (t & 7) ^ (r6 & 7);
    const char* srcA = (const char*)encf + (size_t)(m0 + r6) * 4096 + gsA * 16;
    const int r2  = t >> 2;                        // B: 0..127, key row&3 (4 slots/64B row)
    const int gsB = (t & 3) ^ (r2 & 3);
    const char* srcB = (const char*)w1bt + (size_t)(n0 + r2) * 2048 + gsB * 16;

#define STAGE_A(D, T) do { \
    _Pragma("unroll") \
    for (int h = 0; h < 4; ++h) \
        __builtin_amdgcn_global_load_lds( \
            (const __attribute__((address_space(1))) unsigned int*)(srcA + (size_t)h * 262144 + (size_t)(T) * 128), \
            (__attribute__((address_space(3))) unsigned int*)(smem + (D) * 49152 + h * 8192 + t * 16), 16, 0, 0); \
} while (0)
#define STAGE_B(D, T) do { \
    _Pragma("unroll") \
    for (int h = 0; h < 2; ++h) \
        __builtin_amdgcn_global_load_lds( \
            (const __attribute__((address_space(1))) unsigned int*)(srcB + (size_t)h * 262144 + (size_t)(T) * 64), \
            (__attribute__((address_space(3))) unsigned int*)(smem + (D) * 49152 + 32768 + h * 8192 + t * 16), 16, 0, 0); \
} while (0)

    // fragment read bases
    const int rbA = wr * 128 + l15;                          // + m*16
    const int rbB = wc * 64 + l15;                           // + n*16
    const int sAlo = ((2 * g) ^ (l15 & 7)) << 4;             // f32 lo half (k g*8..g*8+3)
    const int sAhi = ((2 * g + 1) ^ (l15 & 7)) << 4;         // f32 hi half
    const int sB   = (g ^ (l15 & 3)) << 4;

    f32x4 acc[8][4] = {};
    bf16x8 fa[8], fb[4];

    float wv[4];
    int gcol[4];
#pragma unroll
    for (int n = 0; n < 4; ++n) {
        gcol[n] = n0 + wc * 64 + n * 16 + l15;
        wv[n] = w2[gcol[n]];
    }

#define RDFRAGS(D) do { \
    _Pragma("unroll") \
    for (int m = 0; m < 8; ++m) { \
        const char* _p = smem + (D) * 49152 + (rbA + m * 16) * 128; \
        f32x4 lo = *(const f32x4*)(_p + sAlo); \
        f32x4 hi = *(const f32x4*)(_p + sAhi); \
        bf16x8 a; \
        a[0]=(bf16)lo[0]; a[1]=(bf16)lo[1]; a[2]=(bf16)lo[2]; a[3]=(bf16)lo[3]; \
        a[4]=(bf16)hi[0]; a[5]=(bf16)hi[1]; a[6]=(bf16)hi[2]; a[7]=(bf16)hi[3]; \
        fa[m] = a; \
    } \
    _Pragma("unroll") \
    for (int n = 0; n < 4; ++n) \
        fb[n] = *(const bf16x8*)(smem + (D) * 49152 + 32768 + (rbB + n * 16) * 64 + sB); \
} while (0)

#define MFMA32() do { \
    PRIO1; \
    _Pragma("unroll") \
    for (int m = 0; m < 8; ++m) \
        _Pragma("unroll") \
        for (int n = 0; n < 4; ++n) \
            acc[m][n] = __builtin_amdgcn_mfma_f32_16x16x32_bf16(fa[m], fb[n], acc[m][n], 0, 0, 0); \
    PRIO0; \
} while (0)

    // prologue: stage tiles 0,1 into bufs 0,1; wait tile0 (leave tile1's 6 in flight)
    STAGE_A(0, 0); STAGE_B(0, 0);
    STAGE_A(1, 1); STAGE_B(1, 1);
    VMC6; SBAR;

    // main loop: iters 0..29 (unroll-3 for static ring index); iter t computes buf t%3,
    // stages tile t+2 -> buf (t+2)%3 (restage-safe: last read at iter t-1, behind SBAR).
#pragma unroll 1
    for (int tt = 0; tt < 30; tt += 3) {
        RDFRAGS(0);
        STAGE_A(2, tt + 2); STAGE_B(2, tt + 2);
        MFMA32();
        VMC6; SBAR;          // tile tt+1 complete; tt+2's 6 in flight

        RDFRAGS(1);
        STAGE_A(0, tt + 3); STAGE_B(0, tt + 3);
        MFMA32();
        VMC6; SBAR;

        RDFRAGS(2);
        STAGE_A(1, tt + 4); STAGE_B(1, tt + 4);
        MFMA32();
        VMC6; SBAR;
    }
    // tail: iter 30 (buf 0), iter 31 (buf 1) — no staging left
    RDFRAGS(0);
    MFMA32();
    VMC0; SBAR;              // tile 31 complete
    RDFRAGS(1);
    MFMA32();

    // epilogue: h = tanh(acc + cvec); e[row] += h . w2
    float cv[4];
#pragma unroll
    for (int n = 0; n < 4; ++n) cv[n] = cvec[b * 1024 + gcol[n]];
#pragma unroll
    for (int m = 0; m < 8; ++m) {
#pragma unroll
        for (int r = 0; r < 4; ++r) {
            float s = 0.f;
#pragma unroll
            for (int n = 0; n < 4; ++n)
                s += fast_tanh(acc[m][n][r] + cv[n]) * wv[n];
            s += __shfl_xor(s, 1); s += __shfl_xor(s, 2);
            s += __shfl_xor(s, 4); s += __shfl_xor(s, 8);
            if (l15 == 0)
                atomicAdd(&ebuf[m0 + wr * 128 + m * 16 + g * 4 + r], s);
        }
    }
#undef STAGE_A
#undef STAGE_B
#undef RDFRAGS
#undef MFMA32
}

// ---------------- softmax ----------------
__global__ void k_softmax(const float* __restrict__ ebuf, float* __restrict__ alpha) {
    int bb = blockIdx.x, t = threadIdx.x;
    __shared__ float red[4], red2[4];
    float v[8];
    float mx = -1e30f;
#pragma unroll
    for (int i = 0; i < 8; ++i) { v[i] = ebuf[bb * 2048 + i * 256 + t]; mx = fmaxf(mx, v[i]); }
    for (int o = 32; o > 0; o >>= 1) mx = fmaxf(mx, __shfl_xor(mx, o));
    if ((t & 63) == 0) red[t >> 6] = mx;
    __syncthreads();
    mx = fmaxf(fmaxf(red[0], red[1]), fmaxf(red[2], red[3]));
    float sum = 0.f;
#pragma unroll
    for (int i = 0; i < 8; ++i) { v[i] = __expf(v[i] - mx); sum += v[i]; }
    for (int o = 32; o > 0; o >>= 1) sum += __shfl_xor(sum, o);
    if ((t & 63) == 0) red2[t >> 6] = sum;
    __syncthreads();
    sum = red2[0] + red2[1] + red2[2] + red2[3];
    float inv = 1.f / sum;
#pragma unroll
    for (int i = 0; i < 8; ++i) alpha[bb * 2048 + i * 256 + t] = v[i] * inv;
}

// ---------------- context from f32 enc, atomic-direct to out ----------------
__global__ void k_ctx_f(const float* __restrict__ enc, const float* __restrict__ alpha,
                        float* __restrict__ out) {
    int bid = blockIdx.x;                     // 512 = 32 b x 16 sc
    int bb = bid >> 4, sc = bid & 15;
    int t = threadIdx.x;                      // 256, each owns 4 floats of D
    __shared__ float al[128];
    if (t < 128) al[t] = alpha[bb * 2048 + sc * 128 + t];
    __syncthreads();
    f32x4 acc = {0.f, 0.f, 0.f, 0.f};
    const f32x4* base = (const f32x4*)(enc + ((size_t)bb * 2048 + sc * 128) * 1024) + t;
    for (int s = 0; s < 128; ++s) {
        f32x4 vv = base[(size_t)s * 256];
        acc += vv * al[s];
    }
    float* o = out + (size_t)bb * 1024 + t * 4;
    atomicAdd(&o[0], acc[0]);
    atomicAdd(&o[1], acc[1]);
    atomicAdd(&o[2], acc[2]);
    atomicAdd(&o[3], acc[3]);
}

// ================= fallback path (small workspace) =================
__global__ void k_hid_partial(const float* __restrict__ hid, const float* __restrict__ W1,
                              float* __restrict__ hidp) {
    int e = blockIdx.x * 256 + threadIdx.x;
    int dch = blockIdx.y;
    float acc[32];
#pragma unroll
    for (int b = 0; b < 32; ++b) acc[b] = 0.f;
    int d0 = dch * 128;
    for (int dd = 0; dd < 128; ++dd) {
        int d = d0 + dd;
        float w = W1[(size_t)(1024 + d) * 1024 + e];
#pragma unroll
        for (int b = 0; b < 32; ++b) acc[b] += hid[b * 1024 + d] * w;
    }
#pragma unroll
    for (int b = 0; b < 32; ++b) hidp[((size_t)dch * 32 + b) * 1024 + e] = acc[b];
}

__global__ void k_hid_reduce(const float* __restrict__ hidp, const float* __restrict__ b1,
                             float* __restrict__ cvec) {
    int i = blockIdx.x * 256 + threadIdx.x;
    int e = i & 1023;
    float s = b1[e];
#pragma unroll
    for (int dch = 0; dch < 8; ++dch) s += hidp[(size_t)dch * 32768 + i];
    cvec[i] = s;
}

__global__ void k_w1t(const float* __restrict__ W1, bf16* __restrict__ w1bt) {
    __shared__ float tile[32][33];
    int tx = threadIdx.x, ty = threadIdx.y;
    int bx = blockIdx.x, by = blockIdx.y;
#pragma unroll
    for (int i = 0; i < 4; ++i)
        tile[ty + i * 8][tx] = W1[(size_t)(by * 32 + ty + i * 8) * 1024 + bx * 32 + tx];
    __syncthreads();
#pragma unroll
    for (int i = 0; i < 4; ++i)
        w1bt[(size_t)(bx * 32 + ty + i * 8) * 1024 + by * 32 + tx] = (bf16)tile[tx][ty + i * 8];
}

__global__ __launch_bounds__(256, 3) void k_gemm_e(
    const float* __restrict__ enc, const bf16* __restrict__ w1bt,
    const float* __restrict__ cvec, const float* __restrict__ w2,
    float* __restrict__ ebuf)
{
    __shared__ __align__(16) unsigned char smem[24 * 1024];
    const int t = threadIdx.x;
    const int lane = t & 63;
    const int w = t >> 6;
    const int wr = w >> 1, wc = w & 1;
    const int l15 = lane & 15, g = lane >> 4;

    unsigned raw = blockIdx.x;
    unsigned swz = (raw & 7u) * 512u + (raw >> 3);
    const int nt = swz & 7, mt = swz >> 3;
    const int m0 = mt * 128, n0 = nt * 128;
    const int b = m0 >> 11;

    int rowA = (t >> 3);
    int slotA = (t & 7) ^ (rowA & 7);
    const char* gA0 = (const char*)enc + (size_t)(m0 + rowA) * 4096 + slotA * 16;
    int rowB = (t >> 2);
    int slotB = (t & 3) ^ ((t >> 3) & 3);
    const char* gB0 = (const char*)w1bt + (size_t)(n0 + rowB) * 2048 + slotB * 16;

    int rowA0 = wr * 64 + l15;
    unsigned offA0 = (unsigned)rowA0 * 128 + ((((2 * g)) ^ (l15 & 7)) << 4);
    int rowB0 = wc * 64 + l15;
    unsigned offB0 = 16384u + (unsigned)rowB0 * 64 + (((g ^ ((l15 >> 1) & 3))) << 4);

    f32x4 acc[4][4] = {};

    for (int kt = 0; kt < 32; ++kt) {
        const char* pa = gA0 + kt * 128;
        const char* pb = gB0 + kt * 64;
#pragma unroll
        for (int c = 0; c < 4; ++c)
            __builtin_amdgcn_global_load_lds(
                (const __attribute__((address_space(1))) unsigned int*)(pa + (size_t)c * 131072),
                (__attribute__((address_space(3))) unsigned int*)(smem + c * 4096 + w * 1024), 16, 0, 0);
#pragma unroll
        for (int c = 0; c < 2; ++c)
            __builtin_amdgcn_global_load_lds(
                (const __attribute__((address_space(1))) unsigned int*)(pb + (size_t)c * 131072),
                (__attribute__((address_space(3))) unsigned int*)(smem + 16384 + c * 4096 + w * 1024), 16, 0, 0);
        __syncthreads();

        bf16x8 af[4], bfr[4];
#pragma unroll
        for (int m = 0; m < 4; ++m) {
            unsigned o0 = offA0 + m * 2048;
            f32x4 lo = *(const f32x4*)(smem + o0);
            f32x4 hi = *(const f32x4*)(smem + (o0 ^ 16u));
            bf16x8 a;
            a[0] = (bf16)lo[0]; a[1] = (bf16)lo[1]; a[2] = (bf16)lo[2]; a[3] = (bf16)lo[3];
            a[4] = (bf16)hi[0]; a[5] = (bf16)hi[1]; a[6] = (bf16)hi[2]; a[7] = (bf16)hi[3];
            af[m] = a;
        }
#pragma unroll
        for (int n = 0; n < 4; ++n)
            bfr[n] = *(const bf16x8*)(smem + (offB0 + n * 1024));
#pragma unroll
        for (int m = 0; m < 4; ++m)
#pragma unroll
            for (int n = 0; n < 4; ++n)
                acc[m][n] = __builtin_amdgcn_mfma_f32_16x16x32_bf16(af[m], bfr[n], acc[m][n], 0, 0, 0);
        __syncthreads();
    }

    float cv[4], wv[4];
#pragma unroll
    for (int n = 0; n < 4; ++n) {
        int gcol = n0 + wc * 64 + n * 16 + l15;
        cv[n] = cvec[b * 1024 + gcol];
        wv[n] = w2[gcol];
    }
#pragma unroll
    for (int m = 0; m < 4; ++m) {
#pragma unroll
        for (int r = 0; r < 4; ++r) {
            float s = 0.f;
#pragma unroll
            for (int n = 0; n < 4; ++n)
                s += fast_tanh(acc[m][n][r] + cv[n]) * wv[n];
            s += __shfl_xor(s, 1); s += __shfl_xor(s, 2);
            s += __shfl_xor(s, 4); s += __shfl_xor(s, 8);
            if (l15 == 0)
                atomicAdd(&ebuf[m0 + wr * 64 + m * 16 + g * 4 + r], s);
        }
    }
}

__global__ void k_ctx_partial(const float* __restrict__ enc, const float* __restrict__ alpha,
                              float* __restrict__ ctxp) {
    int bid = blockIdx.x;
    int bb = bid >> 4, sc = bid & 15;
    int t = threadIdx.x;
    __shared__ float al[128];
    if (t < 128) al[t] = alpha[bb * 2048 + sc * 128 + t];
    __syncthreads();
    f32x4 acc = {0.f, 0.f, 0.f, 0.f};
    const f32x4* base = (const f32x4*)(enc + ((size_t)bb * 2048 + sc * 128) * 1024) + t;
    for (int s = 0; s < 128; ++s) {
        f32x4 vv = base[(size_t)s * 256];
        acc += vv * al[s];
    }
    *((f32x4*)(ctxp + (size_t)bid * 1024) + t) = acc;
}

__global__ void k_ctx_reduce(const float* __restrict__ ctxp, float* __restrict__ out) {
    int i = blockIdx.x * 256 + threadIdx.x;
    int bb = i >> 10, d = i & 1023;
    float s = 0.f;
#pragma unroll
    for (int sc = 0; sc < 16; ++sc) s += ctxp[((size_t)(bb * 16 + sc)) * 1024 + d];
    out[i] = s;
}

extern "C" void kernel_launch(void* const* d_in, const int* in_sizes, int n_in,
                              void* d_out, int out_size, void* d_ws, size_t ws_size,
                              hipStream_t stream) {
    const float* hid = (const float*)d_in[0];
    const float* enc = (const float*)d_in[1];
    const float* W1  = (const float*)d_in[2];
    const float* b1  = (const float*)d_in[3];
    const float* w2  = (const float*)d_in[4];
    float* out = (float*)d_out;
    char* ws = (char*)d_ws;

    if (ws_size >= O_TOTAL) {
        bf16*  w1bt  = (bf16*)(ws + P_W1BT);
        float* cvec  = (float*)(ws + P_C);
        float* ebuf  = (float*)(ws + P_E);
        float* alpha = (float*)(ws + P_ALPHA);

        k_pre<<<1536, 256, 0, stream>>>(W1, b1, w1bt, cvec, ebuf, out);
        k_hid_atomic<<<dim3(4, 32), 256, 0, stream>>>(hid, W1, cvec);
        k_gemm9<<<1024, 512, 0, stream>>>(enc, w1bt, cvec, w2, ebuf);
        k_softmax<<<32, 256, 0, stream>>>(ebuf, alpha);
        k_ctx_f<<<512, 256, 0, stream>>>(enc, alpha, out);
    } else {
        bf16*  w1bt  = (bf16*)(ws + O_W1BT);
        float* cvec  = (float*)(ws + O_C);
        float* ebuf  = (float*)(ws + O_E);
        float* alpha = (float*)(ws + O_ALPHA);
        float* hidp  = (float*)(ws + O_HIDP);
        float* ctxp  = (float*)(ws + O_CTXP);

        hipMemsetAsync(ebuf, 0, 65536 * sizeof(float), stream);
        k_hid_partial<<<dim3(4, 8), 256, 0, stream>>>(hid, W1, hidp);
        k_w1t<<<dim3(32, 32), dim3(32, 8), 0, stream>>>(W1, w1bt);
        k_hid_reduce<<<128, 256, 0, stream>>>(hidp, b1, cvec);
        k_gemm_e<<<4096, 256, 0, stream>>>(enc, w1bt, cvec, w2, ebuf);
        k_softmax<<<32, 256, 0, stream>>>(ebuf, alpha);
        k_ctx_partial<<<512, 256, 0, stream>>>(enc, alpha, ctxp);
        k_ctx_reduce<<<128, 256, 0, stream>>>(ctxp, out);
    }
}